// Round 1
// baseline (962.029 us; speedup 1.0000x reference)
//
#include <hip/hip_runtime.h>
#include <hip/hip_bf16.h>

// Symmetric contraction (MACE-style), B=2048, C=256, I=9, E=10.
// Strategy:
//   out_s[b,c]   = sum_k Wy3s[b,c,k] * P3[k](x)  + sum_k Wy2s * P2[k] + Wy1s * P1
//   out_v[b,c,a] = same with vector tables (W has no 'a' index; U does)
// where P3[k] = sum_{i<=j<=l} Sym3[m(i,j,l),k] * x_i x_j x_l (symmetrized U3),
// Wy[b,c,k] = sum_e y[b,e] W[e,k,c].
// prep kernel: symmetrize U into a packed table in d_ws (rebuilt every call;
// ws is re-poisoned by the harness).
// main kernel: 1 thread per (b,c); Wy in registers; x in LDS (runtime-indexed,
// own column only -> no barrier); Sym rows are wave-uniform -> scalar loads.

#define NB 2048
#define NC 256
#define NI 9
#define NE 10

#define N_TRI 165   // C(9+2,3)
#define N_PAIR 45   // C(9+1,2)

#define ROW3 128    // 23 scalar + 3*30 vector = 113, padded
#define ROW2 16     // 3 scalar + 3*4 vector = 15, padded
#define ROW1 4      // 1 scalar + 3 vector

#define OFF3 0
#define OFF2 (N_TRI * ROW3)            // 21120
#define OFF1 (OFF2 + N_PAIR * ROW2)    // 21840
// total tab floats: 21876 (~87.5 KB) in d_ws

__global__ __launch_bounds__(256) void sc_prep(
    const float* __restrict__ U1_s, const float* __restrict__ U2_s,
    const float* __restrict__ U3_s, const float* __restrict__ U1_v,
    const float* __restrict__ U2_v, const float* __restrict__ U3_v,
    float* __restrict__ tab)
{
    const int tid = threadIdx.x;
    if (tid < N_TRI) {
        // decode sorted triple (ii <= jj <= kk) from linear index
        int m = tid, ii = 0, jj = 0, kk = 0, cnt = 0;
        for (int i = 0; i < NI; i++)
            for (int j = i; j < NI; j++)
                for (int k = j; k < NI; k++) {
                    if (cnt == m) { ii = i; jj = j; kk = k; }
                    cnt++;
                }
        // distinct permutations of the multiset {ii,jj,kk}
        int P[6][3]; int np;
        if (ii == jj && jj == kk) {
            np = 1;
            P[0][0] = ii; P[0][1] = ii; P[0][2] = ii;
        } else if (ii == jj) {       // (i,i,k)
            np = 3;
            P[0][0] = ii; P[0][1] = ii; P[0][2] = kk;
            P[1][0] = ii; P[1][1] = kk; P[1][2] = ii;
            P[2][0] = kk; P[2][1] = ii; P[2][2] = ii;
        } else if (jj == kk) {       // (i,j,j)
            np = 3;
            P[0][0] = ii; P[0][1] = jj; P[0][2] = jj;
            P[1][0] = jj; P[1][1] = ii; P[1][2] = jj;
            P[2][0] = jj; P[2][1] = jj; P[2][2] = ii;
        } else {                     // all distinct: 6 perms
            np = 6;
            P[0][0] = ii; P[0][1] = jj; P[0][2] = kk;
            P[1][0] = ii; P[1][1] = kk; P[1][2] = jj;
            P[2][0] = jj; P[2][1] = ii; P[2][2] = kk;
            P[3][0] = jj; P[3][1] = kk; P[3][2] = ii;
            P[4][0] = kk; P[4][1] = ii; P[4][2] = jj;
            P[5][0] = kk; P[5][1] = jj; P[5][2] = ii;
        }
        float* row = tab + OFF3 + m * ROW3;
        for (int t = 0; t < 23; t++) {
            float s = 0.f;
            for (int p = 0; p < np; p++)
                s += U3_s[((P[p][0] * NI + P[p][1]) * NI + P[p][2]) * 23 + t];
            row[t] = s;
        }
        for (int a = 0; a < 3; a++)
            for (int t = 0; t < 30; t++) {
                float s = 0.f;
                for (int p = 0; p < np; p++)
                    s += U3_v[(((a * NI + P[p][0]) * NI + P[p][1]) * NI + P[p][2]) * 30 + t];
                row[23 + a * 30 + t] = s;
            }
    } else if (tid < N_TRI + N_PAIR) {
        int m = tid - N_TRI, ii = 0, jj = 0, cnt = 0;
        for (int i = 0; i < NI; i++)
            for (int j = i; j < NI; j++) {
                if (cnt == m) { ii = i; jj = j; }
                cnt++;
            }
        float* row = tab + OFF2 + m * ROW2;
        for (int t = 0; t < 3; t++) {
            float s = U2_s[(ii * NI + jj) * 3 + t];
            if (ii != jj) s += U2_s[(jj * NI + ii) * 3 + t];
            row[t] = s;
        }
        for (int a = 0; a < 3; a++)
            for (int t = 0; t < 4; t++) {
                float s = U2_v[((a * NI + ii) * NI + jj) * 4 + t];
                if (ii != jj) s += U2_v[((a * NI + jj) * NI + ii) * 4 + t];
                row[3 + a * 4 + t] = s;
            }
    } else if (tid < N_TRI + N_PAIR + NI) {
        int i = tid - (N_TRI + N_PAIR);
        float* row = tab + OFF1 + i * ROW1;
        row[0] = U1_s[i];                 // U1_s[i, 0]
        row[1] = U1_v[0 * NI + i];        // U1_v[a, i, 0]
        row[2] = U1_v[1 * NI + i];
        row[3] = U1_v[2 * NI + i];
    }
}

__global__ __launch_bounds__(256) void sc_main(
    const float* __restrict__ x, const float* __restrict__ y,
    const float* __restrict__ W1_s, const float* __restrict__ W2_s,
    const float* __restrict__ W3_s, const float* __restrict__ W1_v,
    const float* __restrict__ W2_v, const float* __restrict__ W3_v,
    const float* __restrict__ tab, float* __restrict__ out)
{
    const int b = blockIdx.x;
    const int c = threadIdx.x;

    // x in LDS: runtime-indexable, each thread touches only its own column
    // (no __syncthreads needed). Lane-consecutive columns -> conflict-free.
    __shared__ float xs[NI][NC];

    float xr[NI];
    {
        const float* xp = x + ((size_t)b * NC + c) * NI;
        #pragma unroll
        for (int i = 0; i < NI; i++) { xr[i] = xp[i]; xs[i][c] = xr[i]; }
    }

    float yr[NE];
    #pragma unroll
    for (int e = 0; e < NE; e++) yr[e] = y[b * NE + e];  // uniform -> s_load

    // ---- Wy[k] = sum_e y[b,e] * W[e,k,c] (coalesced across c) ----
    float wy3s[23], wy2s[3], wy1s;
    float wy3v[30], wy2v[4], wy1v;
    #pragma unroll
    for (int t = 0; t < 23; t++) {
        float s = 0.f;
        #pragma unroll
        for (int e = 0; e < NE; e++) s += yr[e] * W3_s[(e * 23 + t) * NC + c];
        wy3s[t] = s;
    }
    #pragma unroll
    for (int t = 0; t < 3; t++) {
        float s = 0.f;
        #pragma unroll
        for (int e = 0; e < NE; e++) s += yr[e] * W2_s[(e * 3 + t) * NC + c];
        wy2s[t] = s;
    }
    {
        float s = 0.f;
        #pragma unroll
        for (int e = 0; e < NE; e++) s += yr[e] * W1_s[e * NC + c];
        wy1s = s;
    }
    #pragma unroll
    for (int t = 0; t < 30; t++) {
        float s = 0.f;
        #pragma unroll
        for (int e = 0; e < NE; e++) s += yr[e] * W3_v[(e * 30 + t) * NC + c];
        wy3v[t] = s;
    }
    #pragma unroll
    for (int t = 0; t < 4; t++) {
        float s = 0.f;
        #pragma unroll
        for (int e = 0; e < NE; e++) s += yr[e] * W2_v[(e * 4 + t) * NC + c];
        wy2v[t] = s;
    }
    {
        float s = 0.f;
        #pragma unroll
        for (int e = 0; e < NE; e++) s += yr[e] * W1_v[e * NC + c];
        wy1v = s;
    }

    float os = 0.f, ov0 = 0.f, ov1 = 0.f, ov2 = 0.f;

    // ---- correlation 3: 165 sorted triples ----
    {
        const float* r = tab + OFF3;   // advances by ROW3; wave-uniform addr
        for (int i = 0; i < NI; i++) {
            float xi = xs[i][c];
            for (int j = i; j < NI; j++) {
                float xij = xi * xs[j][c];
                for (int k = j; k < NI; k++) {
                    float phi = xij * xs[k][c];
                    float gs = 0.f;
                    #pragma unroll
                    for (int t = 0; t < 23; t++) gs += r[t] * wy3s[t];
                    float g0 = 0.f, g1 = 0.f, g2 = 0.f;
                    #pragma unroll
                    for (int t = 0; t < 30; t++) {
                        g0 += r[23 + t] * wy3v[t];
                        g1 += r[53 + t] * wy3v[t];
                        g2 += r[83 + t] * wy3v[t];
                    }
                    os  += phi * gs;
                    ov0 += phi * g0;
                    ov1 += phi * g1;
                    ov2 += phi * g2;
                    r += ROW3;
                }
            }
        }
    }

    // ---- correlation 2: 45 sorted pairs ----
    {
        const float* r = tab + OFF2;
        for (int i = 0; i < NI; i++) {
            float xi = xs[i][c];
            for (int j = i; j < NI; j++) {
                float phi = xi * xs[j][c];
                float gs = r[0] * wy2s[0] + r[1] * wy2s[1] + r[2] * wy2s[2];
                float g0 = 0.f, g1 = 0.f, g2 = 0.f;
                #pragma unroll
                for (int t = 0; t < 4; t++) {
                    g0 += r[3 + t] * wy2v[t];
                    g1 += r[7 + t] * wy2v[t];
                    g2 += r[11 + t] * wy2v[t];
                }
                os  += phi * gs;
                ov0 += phi * g0;
                ov1 += phi * g1;
                ov2 += phi * g2;
                r += ROW2;
            }
        }
    }

    // ---- correlation 1 ----
    {
        const float* r = tab + OFF1;
        #pragma unroll
        for (int i = 0; i < NI; i++) {
            os  += xr[i] * r[i * ROW1 + 0] * wy1s;
            ov0 += xr[i] * r[i * ROW1 + 1] * wy1v;
            ov1 += xr[i] * r[i * ROW1 + 2] * wy1v;
            ov2 += xr[i] * r[i * ROW1 + 3] * wy1v;
        }
    }

    // out row: [ out_s (256) | out_v (256*3, a fastest) ]
    float* ob = out + (size_t)b * (4 * NC);
    ob[c] = os;
    ob[NC + 3 * c + 0] = ov0;
    ob[NC + 3 * c + 1] = ov1;
    ob[NC + 3 * c + 2] = ov2;
}

extern "C" void kernel_launch(void* const* d_in, const int* in_sizes, int n_in,
                              void* d_out, int out_size, void* d_ws, size_t ws_size,
                              hipStream_t stream) {
    const float* x    = (const float*)d_in[0];
    const float* y    = (const float*)d_in[1];
    const float* U1_s = (const float*)d_in[2];
    const float* U2_s = (const float*)d_in[3];
    const float* U3_s = (const float*)d_in[4];
    const float* U1_v = (const float*)d_in[5];
    const float* U2_v = (const float*)d_in[6];
    const float* U3_v = (const float*)d_in[7];
    const float* W1_s = (const float*)d_in[8];
    const float* W2_s = (const float*)d_in[9];
    const float* W3_s = (const float*)d_in[10];
    const float* W1_v = (const float*)d_in[11];
    const float* W2_v = (const float*)d_in[12];
    const float* W3_v = (const float*)d_in[13];
    float* out = (float*)d_out;
    float* tab = (float*)d_ws;   // ~87.5 KB, rebuilt every call (ws is poisoned)

    sc_prep<<<1, 256, 0, stream>>>(U1_s, U2_s, U3_s, U1_v, U2_v, U3_v, tab);
    sc_main<<<NB, NC, 0, stream>>>(x, y, W1_s, W2_s, W3_s, W1_v, W2_v, W3_v,
                                   tab, out);
}